// Round 3
// baseline (920.661 us; speedup 1.0000x reference)
//
#include <hip/hip_runtime.h>
#include <hip/hip_bf16.h>
#include <cstdint>
#include <cstddef>

// Problem constants
#define T_TOK 8192          // B*S tokens
#define H_DIM 1024
#define I_DIM 4096
#define E_NUM 8
#define NSLOT (T_TOK*2)     // 16384 (token,k) slots
#define ROUTER_BLOCKS 512   // 16 tokens per block

// Workspace layout (byte offsets), total 273 MB.
// y (64MB) overlays xb+wb1 head: xb/wb1 are dead once GEMM2 starts.
#define OFF_CNT     0
#define OFF_PSUM    1024
#define OFF_GATE    32768
#define OFF_ROWMAP  131072
#define OFF_XB      (1ull<<20)      // 16 MB  bf16 x        [1,17) MB
#define OFF_Y       (1ull<<20)      // 64 MB  fp32 y        [1,65) MB (overlay)
#define OFF_WB1     (17ull<<20)     // 64 MB  bf16 W1       [17,81) MB
#define OFF_WB2     (81ull<<20)     // 64 MB  bf16 W2       [81,145) MB
#define OFF_HID     (145ull<<20)    // 128 MB bf16 hidden   [145,273) MB

typedef __attribute__((ext_vector_type(8))) short bf16x8;
typedef __attribute__((ext_vector_type(4))) float f32x4;

__device__ __forceinline__ void gll16(const void* g, void* l) {
    __builtin_amdgcn_global_load_lds((const __attribute__((address_space(1))) void*)g,
                                     (__attribute__((address_space(3))) void*)l, 16, 0, 0);
}

__device__ __forceinline__ ushort f2bf(float f) {   // RNE, finite inputs
    uint32_t u = __float_as_uint(f);
    return (ushort)((u + 0x7FFFu + ((u >> 16) & 1u)) >> 16);
}

__global__ void init_kernel(int* __restrict__ cnt) {
    if (threadIdx.x < E_NUM) cnt[threadIdx.x] = 0;
}

// fp32 -> bf16 bulk conversion, float4 in / ushort4 out, grid-stride.
__global__ __launch_bounds__(256) void f2bf_kernel(const float* __restrict__ s,
                                                   ushort* __restrict__ d, int n4) {
    for (int i = blockIdx.x * 256 + threadIdx.x; i < n4; i += gridDim.x * 256) {
        const float4 v = ((const float4*)s)[i];
        ushort4 o;
        o.x = f2bf(v.x); o.y = f2bf(v.y); o.z = f2bf(v.z); o.w = f2bf(v.w);
        ((ushort4*)d)[i] = o;
    }
}

// fp32 router: one wave per token-quad; exact same math as round-0 baseline.
__global__ __launch_bounds__(256) void router_kernel(
    const float* __restrict__ x, const float* __restrict__ Wr,
    int* __restrict__ cnt, float* __restrict__ psum_part,
    float* __restrict__ gate, int* __restrict__ rowmap)
{
    __shared__ float ps[E_NUM];
    __shared__ int   lcnt[E_NUM];
    __shared__ int   lbase[E_NUM];
    const int tid  = threadIdx.x;
    const int lane = tid & 63;
    const int wid  = tid >> 6;
    if (tid < E_NUM) { ps[tid] = 0.0f; lcnt[tid] = 0; }
    __syncthreads();

    int   e_idx[4][2];
    int   e_pos[4][2];
    float e_w[4][2];

#pragma unroll
    for (int it = 0; it < 4; ++it) {
        const int t = blockIdx.x * 16 + wid * 4 + it;
        const float* xr = x + (size_t)t * H_DIM;
        float xv[16];
#pragma unroll
        for (int j = 0; j < 16; ++j) xv[j] = xr[lane + j * 64];
        float l[E_NUM];
#pragma unroll
        for (int e = 0; e < E_NUM; ++e) {
            const float* wr = Wr + e * H_DIM;
            float s = 0.0f;
#pragma unroll
            for (int j = 0; j < 16; ++j) s += xv[j] * wr[lane + j * 64];
#pragma unroll
            for (int off = 32; off > 0; off >>= 1) s += __shfl_xor(s, off, 64);
            l[e] = s;
        }
        float m = l[0];
#pragma unroll
        for (int e = 1; e < E_NUM; ++e) m = fmaxf(m, l[e]);
        float p[E_NUM], sum = 0.0f;
#pragma unroll
        for (int e = 0; e < E_NUM; ++e) { p[e] = expf(l[e] - m); sum += p[e]; }
        const float inv = 1.0f / sum;
#pragma unroll
        for (int e = 0; e < E_NUM; ++e) p[e] *= inv;
        int i0 = 0;
#pragma unroll
        for (int e = 1; e < E_NUM; ++e) if (p[e] > p[i0]) i0 = e;
        int i1 = (i0 == 0) ? 1 : 0;
#pragma unroll
        for (int e = 0; e < E_NUM; ++e) if (e != i0 && p[e] > p[i1]) i1 = e;
        const float s2 = p[i0] + p[i1];

        if (lane == 0) {
            e_idx[it][0] = i0; e_idx[it][1] = i1;
            e_w[it][0] = p[i0] / s2; e_w[it][1] = p[i1] / s2;
            e_pos[it][0] = atomicAdd(&lcnt[i0], 1);
            e_pos[it][1] = atomicAdd(&lcnt[i1], 1);
#pragma unroll
            for (int e = 0; e < E_NUM; ++e) atomicAdd(&ps[e], p[e]);
        }
    }
    __syncthreads();
    if (tid < E_NUM) {
        lbase[tid] = atomicAdd(&cnt[tid], lcnt[tid]);
        psum_part[blockIdx.x * E_NUM + tid] = ps[tid];
    }
    __syncthreads();
    if (lane == 0) {
#pragma unroll
        for (int it = 0; it < 4; ++it) {
            const int t = blockIdx.x * 16 + wid * 4 + it;
#pragma unroll
            for (int k = 0; k < 2; ++k) {
                const int e = e_idx[it][k];
                const int pos = lbase[e] + e_pos[it][k];
                rowmap[e * T_TOK + pos] = 2 * t + k;
                gate[2 * t + k] = e_w[it][k];
            }
        }
    }
}

// Gathered bf16 MFMA GEMM (NT): Out[slot,n] = act(sum_k A[row(slot),k]*W[e,n,k] + bias[e,n])
// 128x128 tile, BK=32, 4 waves, 16x16x32 MFMA, 4x4 frags/wave.
// Staging: global_load_lds width16, XOR-swizzled global source (rule #21);
// ds_read applies the same XOR -> 2-way banks (free).
template<int N, int K, bool FIRST>
__global__ __launch_bounds__(256) void moe_gemm_mfma(
    const ushort* __restrict__ A,    // bf16: FIRST? xb [T,H] : hidden [NSLOT,I]
    const ushort* __restrict__ W,    // bf16 [E,N,K]
    const float* __restrict__ bias,  // fp32 [E,N]
    ushort* __restrict__ OutBf,      // FIRST: hidden [NSLOT,N]
    float* __restrict__ OutF,        // !FIRST: y [NSLOT,N]
    const int* __restrict__ rowmap,
    const int* __restrict__ cnt)
{
    const int e  = blockIdx.z;
    const int cnt_e = cnt[e];
    const int row0 = blockIdx.y * 128;
    if (row0 >= cnt_e) return;
    const int col0 = blockIdx.x * 128;

    __shared__ int    sslot[128];
    __shared__ ushort lA[128 * 32];
    __shared__ ushort lB[128 * 32];

    const int tid = threadIdx.x, lane = tid & 63, w = tid >> 6;
    if (tid < 128) {
        const int r = row0 + tid;
        sslot[tid] = (r < cnt_e) ? rowmap[e * T_TOK + r] : -1;
    }
    __syncthreads();

    // staging: per wave 2 calls each for A and B; call covers 16 rows x 32 k.
    const int rsub = lane >> 2;      // row within 16-row call
    const int s4   = lane & 3;       // dest 16B slot within row
    const ushort* gA[2]; const ushort* gB[2];
    ushort* ldA[2]; ushort* ldB[2];
#pragma unroll
    for (int c = 0; c < 2; ++c) {
        const int r = (w * 2 + c) * 16 + rsub;       // local row 0..127
        const int g = s4 ^ ((r >> 1) & 3);           // inverse-swizzled source chunk
        int srow = sslot[r]; if (srow < 0) srow = 0; // pad rows: any valid addr
        const int arow = FIRST ? (srow >> 1) : srow;
        gA[c]  = A + (size_t)arow * K + g * 8;
        gB[c]  = W + ((size_t)e * N + col0 + r) * K + g * 8;
        ldA[c] = &lA[(w * 2 + c) * 512];
        ldB[c] = &lB[(w * 2 + c) * 512];
    }

    // fragment ds_read offsets (same XOR as source swizzle)
    const int fr = lane & 15;
    const int kq = lane >> 4;
    int offA[4], offB[4];
#pragma unroll
    for (int i = 0; i < 4; ++i) {
        const int r  = (w >> 1) * 64 + i * 16 + fr;
        offA[i] = r * 32 + (kq ^ ((r >> 1) & 3)) * 8;
        const int cr = (w & 1) * 64 + i * 16 + fr;
        offB[i] = cr * 32 + (kq ^ ((cr >> 1) & 3)) * 8;
    }

    f32x4 acc[4][4] = {};
    for (int kt = 0; kt < K; kt += 32) {
#pragma unroll
        for (int c = 0; c < 2; ++c) {
            gll16(gA[c] + kt, ldA[c]);
            gll16(gB[c] + kt, ldB[c]);
        }
        __syncthreads();                 // compiler drains vmcnt before barrier
        bf16x8 af[4], bfr[4];
#pragma unroll
        for (int i = 0; i < 4; ++i) {
            af[i]  = *(const bf16x8*)&lA[offA[i]];
            bfr[i] = *(const bf16x8*)&lB[offB[i]];
        }
#pragma unroll
        for (int mi = 0; mi < 4; ++mi)
#pragma unroll
            for (int ni = 0; ni < 4; ++ni)
                acc[mi][ni] = __builtin_amdgcn_mfma_f32_16x16x32_bf16(
                    af[mi], bfr[ni], acc[mi][ni], 0, 0, 0);
        __syncthreads();                 // all reads done before next overwrite
    }

    // epilogue. C/D: col = lane&15, row = (lane>>4)*4 + j   [m89-verified]
    const int wrb = (w >> 1) * 64, wcb = (w & 1) * 64;
    float bb[4];
#pragma unroll
    for (int ni = 0; ni < 4; ++ni) bb[ni] = bias[e * N + col0 + wcb + ni * 16 + fr];
    const int rowhi = lane >> 4;
#pragma unroll
    for (int mi = 0; mi < 4; ++mi) {
#pragma unroll
        for (int j = 0; j < 4; ++j) {
            const int r = wrb + mi * 16 + rowhi * 4 + j;
            if (row0 + r < cnt_e) {
                const int slot = sslot[r];
#pragma unroll
                for (int ni = 0; ni < 4; ++ni) {
                    const int cg = col0 + wcb + ni * 16 + fr;
                    float v = acc[mi][ni][j] + bb[ni];
                    if (FIRST) {
                        v = 0.5f * v * (1.0f + erff(v * 0.70710678118654752f));
                        OutBf[(size_t)slot * N + cg] = f2bf(v);
                    } else {
                        OutF[(size_t)slot * N + cg] = v;
                    }
                }
            }
        }
    }
}

__global__ __launch_bounds__(256) void combine_kernel(
    const float* __restrict__ y, const float* __restrict__ gate,
    float* __restrict__ out)
{
    const int i  = blockIdx.x * blockDim.x + threadIdx.x;
    const int t  = i >> 8;
    const int hq = (i & 255) * 4;
    const float w0 = gate[2 * t];
    const float w1 = gate[2 * t + 1];
    const float4 a = *(const float4*)(y + (size_t)(2 * t) * H_DIM + hq);
    const float4 b = *(const float4*)(y + (size_t)(2 * t + 1) * H_DIM + hq);
    float4 o;
    o.x = w0 * a.x + w1 * b.x;
    o.y = w0 * a.y + w1 * b.y;
    o.z = w0 * a.z + w1 * b.z;
    o.w = w0 * a.w + w1 * b.w;
    *(float4*)(out + (size_t)t * H_DIM + hq) = o;
}

__global__ void finalize_kernel(const int* __restrict__ cnt,
                                const float* __restrict__ psum_part,
                                float* __restrict__ out_aux)
{
    __shared__ float P[E_NUM];
    __shared__ float F[E_NUM];
    if (threadIdx.x < E_NUM) {
        float s = 0.0f;
        for (int b = 0; b < ROUTER_BLOCKS; ++b) s += psum_part[b * E_NUM + threadIdx.x];
        P[threadIdx.x] = s / (float)T_TOK;
        F[threadIdx.x] = (float)cnt[threadIdx.x] / (float)(T_TOK * 2);
    }
    __syncthreads();
    if (threadIdx.x == 0) {
        float a = 0.0f;
        for (int e = 0; e < E_NUM; ++e) a += F[e] * P[e];
        out_aux[0] = (float)E_NUM * a;
    }
}

extern "C" void kernel_launch(void* const* d_in, const int* in_sizes, int n_in,
                              void* d_out, int out_size, void* d_ws, size_t ws_size,
                              hipStream_t stream)
{
    const float* x  = (const float*)d_in[0];
    const float* Wr = (const float*)d_in[1];
    const float* W1 = (const float*)d_in[2];
    const float* b1 = (const float*)d_in[3];
    const float* W2 = (const float*)d_in[4];
    const float* b2 = (const float*)d_in[5];
    float* out = (float*)d_out;

    char* ws = (char*)d_ws;
    int*    cnt    = (int*)(ws + OFF_CNT);
    float*  psum   = (float*)(ws + OFF_PSUM);
    float*  gate   = (float*)(ws + OFF_GATE);
    int*    rowmap = (int*)(ws + OFF_ROWMAP);
    ushort* xb     = (ushort*)(ws + OFF_XB);
    ushort* wb1    = (ushort*)(ws + OFF_WB1);
    ushort* wb2    = (ushort*)(ws + OFF_WB2);
    ushort* hid    = (ushort*)(ws + OFF_HID);
    float*  yb     = (float*)(ws + OFF_Y);

    hipLaunchKernelGGL(init_kernel, dim3(1), dim3(64), 0, stream, cnt);
    hipLaunchKernelGGL(router_kernel, dim3(ROUTER_BLOCKS), dim3(256), 0, stream,
                       x, Wr, cnt, psum, gate, rowmap);
    hipLaunchKernelGGL(f2bf_kernel, dim3(2048), dim3(256), 0, stream,
                       x, xb, T_TOK * H_DIM / 4);
    hipLaunchKernelGGL(f2bf_kernel, dim3(2048), dim3(256), 0, stream,
                       W1, wb1, E_NUM * I_DIM * H_DIM / 4);
    hipLaunchKernelGGL(f2bf_kernel, dim3(2048), dim3(256), 0, stream,
                       W2, wb2, E_NUM * H_DIM * I_DIM / 4);
    hipLaunchKernelGGL((moe_gemm_mfma<I_DIM, H_DIM, true>),
                       dim3(I_DIM / 128, T_TOK / 128, E_NUM), dim3(256), 0, stream,
                       xb, wb1, b1, hid, nullptr, rowmap, cnt);
    hipLaunchKernelGGL((moe_gemm_mfma<H_DIM, I_DIM, false>),
                       dim3(H_DIM / 128, T_TOK / 128, E_NUM), dim3(256), 0, stream,
                       hid, wb2, b2, nullptr, yb, rowmap, cnt);
    hipLaunchKernelGGL(combine_kernel, dim3((T_TOK * H_DIM / 4) / 256), dim3(256), 0, stream,
                       yb, gate, out);
    hipLaunchKernelGGL(finalize_kernel, dim3(1), dim3(64), 0, stream,
                       cnt, psum, out + (size_t)T_TOK * H_DIM);
}